// Round 16
// baseline (69.770 us; speedup 1.0000x reference)
//
#include <hip/hip_runtime.h>
#include <stdint.h>

typedef unsigned long long u64;

#define BB 4
#define NN 32768
#define CC 3
#define PRE 4096      // reference top_k size (fallback path only)
#define RNK 768       // ranked prefix needed by the fast path (= ROWS_A)
#define POST 512
#define TH 0.7f
#define ROWS_A 768
#define RW (ROWS_A / 64)
#define RS_TILE 2560  // collected-set cap; need RNK <= cnt <= RS_TILE else fallback
#define KPRIME 88     // sample threshold order statistic (of 2048 samples)

__device__ __forceinline__ uint32_t f2u(float f) {
    uint32_t b = __float_as_uint(f);
    return (b & 0x80000000u) ? ~b : (b | 0x80000000u);
}
__device__ __forceinline__ float u2f(uint32_t u) {
    uint32_t b = (u & 0x80000000u) ? (u & 0x7FFFFFFFu) : ~u;
    return __uint_as_float(b);
}
__device__ __forceinline__ float score3(const float* p) {
    return fmaxf(fmaxf(p[0], p[1]), p[2]);
}

// 1) sampled threshold: pb' = p16 of the KPRIME-th largest of 2048 samples
//    (first 2048 elements of the item; iid data => valid sample). 2-pass 8-bit
//    radix select in LDS. Population rank of pb' ~ 88*16 = 1408 +- ~105;
//    P(rank < RNK) ~ 4.9 sigma, P(rank > RS_TILE) ~ 5.9 sigma - both DETECTED
//    (cnt out of [RNK, RS_TILE]) and routed to the exact fallback.
//    Also zeroes cnt[b]. scal: [0..3]=cnt, [12..15]=pb.
__global__ void __launch_bounds__(256) k_sample(const float* __restrict__ cls,
                                                uint32_t* __restrict__ scal) {
    int b = blockIdx.x;
    int tid = threadIdx.x;
    __shared__ uint16_t sp[2048];
    __shared__ uint32_t hist[256];
    __shared__ uint32_t s_hi, s_rem;
    for (int s = 0; s < 8; ++s) {
        int i = s * 256 + tid;   // sample = element i (coalesced)
        sp[i] = (uint16_t)(f2u(score3(cls + ((size_t)b * NN + i) * CC)) >> 16);
    }
    hist[tid] = 0;
    __syncthreads();
    for (int s = 0; s < 8; ++s) atomicAdd(&hist[sp[s * 256 + tid] >> 8], 1u);
    __syncthreads();
    if (tid == 0) {
        uint32_t need = KPRIME, cum = 0, hb = 0;
        for (int d = 255; d >= 0; --d) {
            if (need <= cum + hist[d]) { hb = (uint32_t)d; s_rem = need - cum; break; }
            cum += hist[d];
        }
        s_hi = hb;
    }
    __syncthreads();
    uint32_t hb = s_hi, rem = s_rem;
    hist[tid] = 0;
    __syncthreads();
    for (int s = 0; s < 8; ++s) {
        uint16_t v = sp[s * 256 + tid];
        if ((uint32_t)(v >> 8) == hb) atomicAdd(&hist[v & 255], 1u);
    }
    __syncthreads();
    if (tid == 0) {
        uint32_t need = rem, cum = 0, lb = 0;
        for (int d = 255; d >= 0; --d) {
            if (need <= cum + hist[d]) { lb = (uint32_t)d; break; }
            cum += hist[d];
        }
        scal[12 + b] = (hb << 8) | lb;   // pb'
        scal[b] = 0;                     // cnt
    }
}

// 2) collect: single pass, p16 >= pb' -> wave-aggregated append into selk.
//    The set {p16 >= pb'} is upward-closed in key order => if RNK <= cnt <= RS_TILE
//    the true top-RNK keys are all collected and union rank == global rank.
__global__ void k_collect(const float* __restrict__ cls, const uint32_t* __restrict__ scal,
                          uint32_t* __restrict__ cnt, u64* __restrict__ selk) {
    int gid = blockIdx.x * blockDim.x + threadIdx.x;   // 512 blocks x 256
    int b = gid >> 15;
    uint32_t pb = scal[12 + b];
    u64 k = ((u64)f2u(score3(cls + (size_t)gid * CC)) << 32)
          | (uint32_t)(~(uint32_t)(gid & (NN - 1)));
    bool sel = (uint32_t)(k >> 48) >= pb;
    u64 mask = __ballot(sel);
    if (sel) {
        int lane = threadIdx.x & 63;
        uint32_t rank = (uint32_t)__popcll(mask & ((1ull << lane) - 1ull));
        int leader = (int)(__ffsll((long long)mask) - 1);
        uint32_t base = 0;
        if (lane == leader) base = atomicAdd(&cnt[b], (uint32_t)__popcll(mask));
        base = (uint32_t)__shfl((int)base, leader, 64);
        uint32_t pos = base + rank;
        if (pos < RS_TILE) selk[(size_t)b * RS_TILE + pos] = k;
    }
}

// 3) rank+scatter over the collected set (~1400 keys): exact counting rank
//    (keys distinct); scatter sidx/ssc/bf iff rank < RNK.
__global__ void __launch_bounds__(256) k_rankscatter(const u64* __restrict__ selk,
                                                     const uint32_t* __restrict__ cnt,
                                                     const float* __restrict__ box,
                                                     int* __restrict__ sidx,
                                                     float* __restrict__ ssc,
                                                     float* __restrict__ bf) {
    const int bpi = RS_TILE / 64;   // 40 blocks per item
    int b = blockIdx.x / bpi;
    int c = blockIdx.x % bpi;
    uint32_t m = cnt[b]; if (m > RS_TILE) m = RS_TILE;
    if ((uint32_t)(c * 64) >= m) return;
    __shared__ u64 tile[RS_TILE];
    uint32_t mp = (m + 7) & ~7u;   // pad to 8; pad value 0 never counts (keys > 0)
    for (uint32_t i = threadIdx.x; i < mp; i += 256)
        tile[i] = (i < m) ? selk[(size_t)b * RS_TILE + i] : 0ull;
    __syncthreads();
    uint32_t k = c * 64 + (threadIdx.x >> 2);
    u64 myk = tile[(k < m) ? k : 0];
    int q = threadIdx.x & 3;
    const ulonglong2* t2 = (const ulonglong2*)tile;
    int cn = 0;
#pragma unroll 8
    for (uint32_t j = 0; j < mp / 8; ++j) {
        ulonglong2 w = t2[4 * j + q];
        cn += (w.x > myk) ? 1 : 0;
        cn += (w.y > myk) ? 1 : 0;
    }
    cn += __shfl_xor(cn, 1, 64);
    cn += __shfl_xor(cn, 2, 64);
    if (q == 0 && k < m && cn < RNK) {
        int r = cn;   // exact global descending rank (keys distinct)
        int n = (int)(~(uint32_t)(myk & 0xFFFFFFFFull));
        sidx[b * RNK + r] = n;
        ssc[b * RNK + r] = u2f((uint32_t)(myk >> 32));
        const float* bp = box + ((size_t)b * NN + n) * 7;
        float x = bp[0], y = bp[1], dx = bp[3], dy = bp[4];
        float* bfb = bf + (size_t)b * 5 * RNK;
        bfb[0 * RNK + r] = x - dx * 0.5f;
        bfb[1 * RNK + r] = x + dx * 0.5f;
        bfb[2 * RNK + r] = y - dy * 0.5f;
        bfb[3 * RNK + r] = y + dy * 0.5f;
        bfb[4 * RNK + r] = dx * dy;
    }
}

// 4) suppression 768x768, transposed word-major: supt[(b*RW + w)*ROWS_A + i]
__global__ void k_iou(const float* __restrict__ bf, u64* __restrict__ supt) {
    const int bpi = ROWS_A / 4;              // 192 blocks per item (4 waves/block)
    int b = blockIdx.x / bpi;
    int wave = threadIdx.x >> 6;
    int lane = threadIdx.x & 63;
    int i = (blockIdx.x % bpi) * 4 + wave;
    const float* bfb = bf + (size_t)b * 5 * RNK;
    float x1 = bfb[0 * RNK + i], x2 = bfb[1 * RNK + i];
    float y1 = bfb[2 * RNK + i], y2 = bfb[3 * RNK + i];
    float ar = bfb[4 * RNK + i];
    u64 myword = 0;
    for (int jw = 0; jw < RW; ++jw) {
        int j = jw * 64 + lane;
        float ix = fminf(x2, bfb[1 * RNK + j]) - fmaxf(x1, bfb[0 * RNK + j]);
        ix = fmaxf(ix, 0.0f);
        float iy = fminf(y2, bfb[3 * RNK + j]) - fmaxf(y1, bfb[2 * RNK + j]);
        iy = fmaxf(iy, 0.0f);
        float inter = __fmul_rn(ix, iy);            // block FMA contraction (match np rounding)
        float uni = (ar + bfb[4 * RNK + j]) - inter;
        float iou = inter / fmaxf(uni, 1e-6f);
        u64 bal = __ballot((iou > TH) && (j > i));
        if (jw == lane) myword = bal;
    }
    if (lane < RW) supt[((size_t)b * RW + lane) * ROWS_A + i] = myword;
}

// 5) fixpoint NMS + output + INLINE exact fallback (4 blocks x 1024).
//    Fast path: Jacobi fixpoint of K[j] = !(exists i: K[i] & sup[i][j]) == greedy
//    (sup[i][j]=0 for j<=i; unique fixpoint by induction). ok = converged &&
//    kept>=POST && RNK <= cnt <= RS_TILE. If !ok: full reference recompute.
__global__ void __launch_bounds__(1024) k_nmsout(const u64* __restrict__ supt,
                                                 const uint32_t* __restrict__ cnt,
                                                 const int* __restrict__ sidx,
                                                 const float* __restrict__ ssc,
                                                 const float* __restrict__ box,
                                                 const float* __restrict__ cls,
                                                 u64* __restrict__ fkey,
                                                 u64* __restrict__ fselk,
                                                 u64* __restrict__ fkr,
                                                 float* __restrict__ fbf,
                                                 float* __restrict__ out) {
    int b = blockIdx.x;
    int tid = threadIdx.x;
    __shared__ u64 keepw[RW], nremw[RW];
    __shared__ uint32_t wpre[65];
    __shared__ int s_changed, s_done;
    const u64* sb = supt + (size_t)b * RW * ROWS_A;

    if (tid < RW) keepw[tid] = ~0ull;
    if (tid == 0) s_done = 0;
    __syncthreads();
    for (int it = 0; it < 48; ++it) {
        if (tid < RW) nremw[tid] = 0;
        if (tid == 0) s_changed = 0;
        __syncthreads();
        // 768 tasks: (word w = tau>>6, 12-row chunk (tau&63)*12); coalesced 96B reads
        for (int tau = tid; tau < ROWS_A; tau += 1024) {
            int w = tau >> 6;
            int r0 = (tau & 63) * 12;
            const u64* wp = sb + (size_t)w * ROWS_A;
            u64 acc = 0;
#pragma unroll
            for (int rr = 0; rr < 12; ++rr) {
                int r = r0 + rr;
                if ((keepw[r >> 6] >> (r & 63)) & 1ull) acc |= wp[r];
            }
            if (acc) atomicOr(&nremw[w], acc);
        }
        __syncthreads();
        if (tid < RW) {
            u64 nk = ~nremw[tid];
            if (nk != keepw[tid]) { s_changed = 1; keepw[tid] = nk; }
        }
        __syncthreads();
        if (!s_changed) { if (tid == 0) s_done = 1; break; }   // uniform exit
    }
    __syncthreads();

    if (tid == 0) {
        uint32_t c = 0;
        for (int w = 0; w < RW; ++w) { wpre[w] = c; c += (uint32_t)__popcll(keepw[w]); }
        wpre[RW] = c;
        uint32_t m = cnt[b];
        bool tileok = (m >= RNK) && (m <= RS_TILE);
        s_changed = (s_done && c >= POST && tileok) ? 1 : 0;   // "fast path ok"
    }
    __syncthreads();

    if (s_changed) {
        // outputs come only from kept rows at rank<768 (suppressed/late d >= nkeep >= POST)
        for (int r = tid; r < ROWS_A; r += 1024) {
            int w = r >> 6, bit = r & 63;
            u64 word = keepw[w];
            if (!((word >> bit) & 1ull)) continue;
            u64 mask = bit ? ((1ull << bit) - 1ull) : 0ull;
            uint32_t d = wpre[w] + (uint32_t)__popcll(word & mask);
            if (d < POST) {
                float* ro = out + ((size_t)b * POST + d) * 7;
                int n = sidx[b * RNK + r];
                const float* bp = box + ((size_t)b * NN + n) * 7;
#pragma unroll
                for (int t = 0; t < 7; ++t) ro[t] = bp[t];
                out[(size_t)BB * POST * 7 + b * POST + d] = ssc[b * RNK + r];
                const float* cp = cls + ((size_t)b * NN + n) * CC;
                float c0 = cp[0], c1 = cp[1], c2 = cp[2];
                int lbl = 0; float bst = c0;
                if (c1 > bst) { bst = c1; lbl = 1; }
                if (c2 > bst) { lbl = 2; }
                out[(size_t)BB * POST * 8 + b * POST + d] = (float)(lbl + 1);
            }
        }
        return;
    }

    // ---------- exact fallback (reference semantics; proven r12 code) ----------
    size_t bo = (size_t)b * NN;
    for (int n = tid; n < NN; n += 1024)
        fkey[bo + n] = ((u64)f2u(score3(cls + (bo + n) * CC)) << 32)
                     | (uint32_t)(~(uint32_t)n);
    __syncthreads();

    __shared__ uint32_t hist[256];
    __shared__ u64 s_prefix;
    __shared__ uint32_t s_k;
    if (tid == 0) { s_prefix = 0; s_k = PRE; }
    __syncthreads();
    for (int pass = 0; pass < 8; ++pass) {
        if (tid < 256) hist[tid] = 0;
        __syncthreads();
        u64 prefix = s_prefix;
        int hi = 8 * pass;
        for (int i = tid; i < NN; i += 1024) {
            u64 k = fkey[bo + i];
            bool match = (pass == 0) || ((k >> (64 - hi)) == prefix);
            if (match) atomicAdd(&hist[(uint32_t)((k >> (56 - hi)) & 255u)], 1u);
        }
        __syncthreads();
        if (tid == 0) {
            uint32_t kneed = s_k, cum = 0; int chosen = 0;
            for (int d = 255; d >= 0; --d) {
                if (kneed <= cum + hist[d]) { chosen = d; break; }
                cum += hist[d];
            }
            s_k = kneed - cum;
            s_prefix = (prefix << 8) | (u64)(uint32_t)chosen;
        }
        __syncthreads();
    }
    u64 kstar = s_prefix;

    __shared__ uint32_t s_cnt;
    if (tid == 0) s_cnt = 0;
    __syncthreads();
    for (int i = tid; i < NN; i += 1024) {
        u64 k = fkey[bo + i];
        if (k >= kstar) {
            uint32_t pos = atomicAdd(&s_cnt, 1u);
            if (pos < PRE) fselk[(size_t)b * PRE + pos] = k;
        }
    }
    __syncthreads();

    __shared__ u64 tile[1024];
    u64 myk0 = fselk[(size_t)b * PRE + tid];
    u64 myk1 = fselk[(size_t)b * PRE + tid + 1024];
    u64 myk2 = fselk[(size_t)b * PRE + tid + 2048];
    u64 myk3 = fselk[(size_t)b * PRE + tid + 3072];
    int rc0 = 0, rc1 = 0, rc2 = 0, rc3 = 0;
    for (int t0 = 0; t0 < PRE; t0 += 1024) {
        tile[tid] = fselk[(size_t)b * PRE + t0 + tid];
        __syncthreads();
#pragma unroll 8
        for (int j = 0; j < 1024; ++j) {
            u64 t = tile[j];
            rc0 += (t > myk0) ? 1 : 0;
            rc1 += (t > myk1) ? 1 : 0;
            rc2 += (t > myk2) ? 1 : 0;
            rc3 += (t > myk3) ? 1 : 0;
        }
        __syncthreads();
    }
    {
        u64 ks[4] = {myk0, myk1, myk2, myk3};
        int rs[4] = {rc0, rc1, rc2, rc3};
#pragma unroll
        for (int j = 0; j < 4; ++j) {
            u64 k = ks[j]; int r = rs[j];
            fkr[(size_t)b * PRE + r] = k;
            int n = (int)(~(uint32_t)(k & 0xFFFFFFFFull));
            const float* bp = box + ((size_t)b * NN + n) * 7;
            float x = bp[0], y = bp[1], dx = bp[3], dy = bp[4];
            float* fb = fbf + (size_t)b * 5 * PRE;
            fb[0 * PRE + r] = x - dx * 0.5f;
            fb[1 * PRE + r] = x + dx * 0.5f;
            fb[2 * PRE + r] = y - dy * 0.5f;
            fb[3 * PRE + r] = y + dy * 0.5f;
            fb[4 * PRE + r] = dx * dy;
        }
    }
    __syncthreads();

    __shared__ u64 km[64];
    const float* fb = fbf + (size_t)b * 5 * PRE;
    if (tid < 64) km[tid] = ~0ull;
    __syncthreads();
    for (int i = 0; i < PRE - 1; ++i) {
        if ((km[i >> 6] >> (i & 63)) & 1ull) {
            float x1 = fb[0 * PRE + i], x2 = fb[1 * PRE + i];
            float y1 = fb[2 * PRE + i], y2 = fb[3 * PRE + i];
            float ar = fb[4 * PRE + i];
            for (int j = i + 1 + tid; j < PRE; j += 1024) {
                float ix = fminf(x2, fb[1 * PRE + j]) - fmaxf(x1, fb[0 * PRE + j]);
                ix = fmaxf(ix, 0.0f);
                float iy = fminf(y2, fb[3 * PRE + j]) - fmaxf(y1, fb[2 * PRE + j]);
                iy = fmaxf(iy, 0.0f);
                float inter = __fmul_rn(ix, iy);
                float uni = (ar + fb[4 * PRE + j]) - inter;
                float iou = inter / fmaxf(uni, 1e-6f);
                if (iou > TH) atomicAnd(&km[j >> 6], ~(1ull << (j & 63)));
            }
        }
        __syncthreads();
    }

    if (tid == 0) {
        uint32_t c = 0;
        for (int w = 0; w < 64; ++w) { wpre[w] = c; c += (uint32_t)__popcll(km[w]); }
        wpre[64] = c;
    }
    __syncthreads();
    uint32_t nkeep = wpre[64];
    for (int r = tid; r < PRE; r += 1024) {
        int w = r >> 6, bit = r & 63;
        u64 word = km[w];
        bool kept = (word >> bit) & 1ull;
        u64 mask = bit ? ((1ull << bit) - 1ull) : 0ull;
        uint32_t before = wpre[w] + (uint32_t)__popcll(word & mask);
        uint32_t d = kept ? before : (nkeep + (uint32_t)r - before);
        if (d < POST) {
            float* ro = out + ((size_t)b * POST + d) * 7;
            float* so = out + (size_t)BB * POST * 7 + b * POST + d;
            float* lo = out + (size_t)BB * POST * 8 + b * POST + d;
            if (kept) {
                u64 k = fkr[(size_t)b * PRE + r];
                int n = (int)(~(uint32_t)(k & 0xFFFFFFFFull));
                const float* bp = box + ((size_t)b * NN + n) * 7;
#pragma unroll
                for (int t = 0; t < 7; ++t) ro[t] = bp[t];
                *so = u2f((uint32_t)(k >> 32));
                const float* cp = cls + ((size_t)b * NN + n) * CC;
                float c0 = cp[0], c1 = cp[1], c2 = cp[2];
                int lbl = 0; float bst = c0;
                if (c1 > bst) { bst = c1; lbl = 1; }
                if (c2 > bst) { lbl = 2; }
                *lo = (float)(lbl + 1);
            } else {
#pragma unroll
                for (int t = 0; t < 7; ++t) ro[t] = 0.0f;
                *so = 0.0f;
                *lo = 1.0f;
            }
        }
    }
}

extern "C" void kernel_launch(void* const* d_in, const int* in_sizes, int n_in,
                              void* d_out, int out_size, void* d_ws, size_t ws_size,
                              hipStream_t stream) {
    const float* cls = (const float*)d_in[0];   // (4, 32768, 3)
    const float* box = (const float*)d_in[1];   // (4, 32768, 7)
    float* out = (float*)d_out;                 // 18432 floats

    char* ws = (char*)d_ws;
    const size_t KB = 1024, MB = 1024 * 1024;
    // No aliasing: every buffer has its own range.
    size_t OFF_SUPT  = 0;                 // 288 KB
    size_t OFF_SELK  = 512 * KB;          // 4 x 2560 x 8 = 80 KB
    size_t OFF_BF    = 640 * KB;          // 60 KB
    size_t OFF_SIDX  = 704 * KB;          // 12 KB
    size_t OFF_SSC   = 716 * KB;          // 12 KB
    size_t OFF_SCAL  = 728 * KB;          // cnt[4], pad, pb[4]
    size_t OFF_FKEY  = 2 * MB;            // 1 MB   (fallback only)
    size_t OFF_FSELK = 3 * MB;            // 128 KB (fallback only)
    size_t OFF_FKR   = 3 * MB + 128 * KB; // 128 KB (fallback only)
    size_t OFF_FBF   = 3 * MB + 256 * KB; // 320 KB (fallback only)

    u64*      supt   = (u64*)(ws + OFF_SUPT);
    u64*      selk   = (u64*)(ws + OFF_SELK);
    float*    bf     = (float*)(ws + OFF_BF);
    int*      sidx   = (int*)(ws + OFF_SIDX);
    float*    ssc    = (float*)(ws + OFF_SSC);
    uint32_t* scal   = (uint32_t*)(ws + OFF_SCAL);
    uint32_t* cnt    = scal;
    u64*      fkey   = (u64*)(ws + OFF_FKEY);
    u64*      fselk  = (u64*)(ws + OFF_FSELK);
    u64*      fkr    = (u64*)(ws + OFF_FKR);
    float*    fbf    = (float*)(ws + OFF_FBF);

    // 5-dispatch chain:
    k_sample<<<BB, 256, 0, stream>>>(cls, scal);
    k_collect<<<(BB * NN) / 256, 256, 0, stream>>>(cls, scal, cnt, selk);
    k_rankscatter<<<BB * (RS_TILE / 64), 256, 0, stream>>>(selk, cnt, box, sidx, ssc, bf);
    k_iou<<<(ROWS_A / 4) * BB, 256, 0, stream>>>(bf, supt);
    k_nmsout<<<BB, 1024, 0, stream>>>(supt, cnt, sidx, ssc, box, cls,
                                      fkey, fselk, fkr, fbf, out);
}

// Round 17
// 64.076 us; speedup vs baseline: 1.0889x; 1.0889x over previous
//
#include <hip/hip_runtime.h>
#include <stdint.h>

typedef unsigned long long u64;

#define BB 4
#define NN 32768
#define CC 3
#define PRE 4096      // reference top_k size (fallback path only)
#define RNK 768       // ranked prefix needed by the fast path (= ROWS_A)
#define POST 512
#define TH 0.7f
#define ROWS_A 768
#define RW (ROWS_A / 64)
#define CANDCAP 2048
#define RS_TILE 2048  // rank tile cap (cnt + ccnt); overflow -> fallback

__device__ __forceinline__ uint32_t f2u(float f) {
    uint32_t b = __float_as_uint(f);
    return (b & 0x80000000u) ? ~b : (b | 0x80000000u);
}
__device__ __forceinline__ float u2f(uint32_t u) {
    uint32_t b = (u & 0x80000000u) ? (u & 0x7FFFFFFFu) : ~u;
    return __uint_as_float(b);
}
__device__ __forceinline__ float score3(const float* p) {
    return fmaxf(fmaxf(p[0], p[1]), p[2]);
}

// 0) zero hist region (uint4 stride) + scalar counters.
//    (custom kernel: rocclr fillBufferAligned costs ~5us in-graph; this ~0.5us)
__global__ void k_zero(uint4* __restrict__ histreg, uint32_t* __restrict__ scal, int n16) {
    int gid = blockIdx.x * blockDim.x + threadIdx.x;
    if (gid < n16) histreg[gid] = make_uint4(0, 0, 0, 0);
    if (gid < 16) scal[gid] = 0;
}

// 1) 2-level histogram of top-16 key bits (1 element/thread, 512 blocks —
//    4x-vectorized 128-block variant regressed; latency-bound atomics want TLP).
//    key = (orderable(score)<<32) | ~index  (distinct keys => exact top_k tie-break)
__global__ void k_hist(const float* __restrict__ cls,
                       uint32_t* __restrict__ hist_f, uint32_t* __restrict__ hist_c) {
    __shared__ uint32_t lc[256];
    lc[threadIdx.x] = 0;
    __syncthreads();
    int gid = blockIdx.x * blockDim.x + threadIdx.x;   // 512 blocks x 256; block spans one item
    int b = gid >> 15;
    uint32_t p16 = f2u(score3(cls + (size_t)gid * CC)) >> 16;
    atomicAdd(&hist_f[((uint32_t)b << 16) + p16], 1u);
    atomicAdd(&lc[p16 >> 8], 1u);
    __syncthreads();
    uint32_t v = lc[threadIdx.x];
    if (v) atomicAdd(&hist_c[((uint32_t)b << 8) + threadIdx.x], v);
}

// 2) collect for the RNK(=768)-th threshold: block re-derives the 16-bit threshold
//    prefix (coarse+fine suffix scans), then definite winners (p16 > pb) ->
//    block-aggregated compaction into selk; boundary bin (p16 == pb) -> cand.
__global__ void __launch_bounds__(256) k_collect(const float* __restrict__ cls,
                                                 const uint32_t* __restrict__ hist_c,
                                                 const uint32_t* __restrict__ hist_f,
                                                 uint32_t* __restrict__ cnt,
                                                 uint32_t* __restrict__ ccnt,
                                                 u64* __restrict__ selk, u64* __restrict__ cand) {
    int tid = threadIdx.x;
    int gid = blockIdx.x * 256 + tid;
    int b = gid >> 15;
    __shared__ uint32_t pref[256];
    __shared__ uint32_t s_selc, s_remc, s_pb;

    uint32_t v = hist_c[((uint32_t)b << 8) + 255 - tid];
    pref[tid] = v;
    __syncthreads();
    for (int off = 1; off < 256; off <<= 1) {
        uint32_t x = (tid >= off) ? pref[tid - off] : 0;
        __syncthreads();
        pref[tid] += x;
        __syncthreads();
    }
    {
        uint32_t after = pref[tid], before = after - v;
        if (before < RNK && RNK <= after) { s_selc = 255 - tid; s_remc = RNK - before; }
    }
    __syncthreads();
    uint32_t selc = s_selc, remc = s_remc;
    uint32_t v2 = hist_f[((uint32_t)b << 16) + (selc << 8) + 255 - tid];
    __syncthreads();
    pref[tid] = v2;
    __syncthreads();
    for (int off = 1; off < 256; off <<= 1) {
        uint32_t x = (tid >= off) ? pref[tid - off] : 0;
        __syncthreads();
        pref[tid] += x;
        __syncthreads();
    }
    {
        uint32_t after = pref[tid], before = after - v2;
        if (before < remc && remc <= after) s_pb = (selc << 8) | (uint32_t)(255 - tid);
    }
    __syncthreads();
    uint32_t pb = s_pb;

    u64 k = ((u64)f2u(score3(cls + (size_t)gid * CC)) << 32)
          | (uint32_t)(~(uint32_t)(gid & (NN - 1)));
    uint32_t p16 = (uint32_t)(k >> 48);
    bool def = p16 > pb;
    u64 mask = __ballot(def);
    int lane = tid & 63;
    int wave = tid >> 6;
    __shared__ uint32_t wtot[4], wbase[4], blockbase;
    uint32_t rank = lane ? (uint32_t)__popcll(mask & ((~0ull) >> (64 - lane))) : 0u;
    if (lane == 0) wtot[wave] = (uint32_t)__popcll(mask);
    __syncthreads();
    if (tid == 0) {
        uint32_t t = 0;
        for (int w = 0; w < 4; ++w) { wbase[w] = t; t += wtot[w]; }
        blockbase = atomicAdd(&cnt[b], t);
    }
    __syncthreads();
    if (def) {
        selk[(size_t)b * RNK + blockbase + wbase[wave] + rank] = k;   // cnt < RNK by pb def
    } else if (p16 == pb) {
        uint32_t pos = atomicAdd(&ccnt[b], 1u);
        if (pos < CANDCAP) cand[(size_t)b * CANDCAP + pos] = k;
    }
}

// 3) union rank+scatter over the ~810-key tile: tile = selk[0..cnt) ++ cand[0..ccnt);
//    union keys (p16>=pb) all beat non-union keys => union rank == global rank.
__global__ void __launch_bounds__(256) k_rankscatter(const u64* __restrict__ selk,
                                                     const u64* __restrict__ cand,
                                                     const uint32_t* __restrict__ cnt,
                                                     const uint32_t* __restrict__ ccnt,
                                                     const float* __restrict__ box,
                                                     int* __restrict__ sidx,
                                                     float* __restrict__ ssc,
                                                     float* __restrict__ bf) {
    const int bpi = RS_TILE / 64;   // 32 blocks per item
    int b = blockIdx.x / bpi;
    int c = blockIdx.x % bpi;
    uint32_t base = cnt[b];
    uint32_t cc = ccnt[b]; if (cc > CANDCAP) cc = CANDCAP;
    uint32_t m = base + cc; if (m > RS_TILE) m = RS_TILE;
    if ((uint32_t)(c * 64) >= m) return;
    __shared__ u64 tile[RS_TILE];
    uint32_t mp = (m + 7) & ~7u;   // pad to 8; pad value 0 never counts (keys > 0)
    for (uint32_t i = threadIdx.x; i < mp; i += 256)
        tile[i] = (i < base) ? selk[(size_t)b * RNK + i]
                : (i < m)    ? cand[(size_t)b * CANDCAP + (i - base)] : 0ull;
    __syncthreads();
    uint32_t k = c * 64 + (threadIdx.x >> 2);
    u64 myk = tile[(k < m) ? k : 0];
    int q = threadIdx.x & 3;
    const ulonglong2* t2 = (const ulonglong2*)tile;
    int cn = 0;
#pragma unroll 8
    for (uint32_t j = 0; j < mp / 8; ++j) {
        ulonglong2 w = t2[4 * j + q];
        cn += (w.x > myk) ? 1 : 0;
        cn += (w.y > myk) ? 1 : 0;
    }
    cn += __shfl_xor(cn, 1, 64);
    cn += __shfl_xor(cn, 2, 64);
    if (q == 0 && k < m && cn < RNK) {
        int r = cn;   // exact global descending rank (keys distinct)
        int n = (int)(~(uint32_t)(myk & 0xFFFFFFFFull));
        sidx[b * RNK + r] = n;
        ssc[b * RNK + r] = u2f((uint32_t)(myk >> 32));
        const float* bp = box + ((size_t)b * NN + n) * 7;
        float x = bp[0], y = bp[1], dx = bp[3], dy = bp[4];
        float* bfb = bf + (size_t)b * 5 * RNK;
        bfb[0 * RNK + r] = x - dx * 0.5f;
        bfb[1 * RNK + r] = x + dx * 0.5f;
        bfb[2 * RNK + r] = y - dy * 0.5f;
        bfb[3 * RNK + r] = y + dy * 0.5f;
        bfb[4 * RNK + r] = dx * dy;
    }
}

// 4) suppression 768x768, transposed word-major: supt[(b*RW + w)*ROWS_A + i]
__global__ void k_iou(const float* __restrict__ bf, u64* __restrict__ supt) {
    const int bpi = ROWS_A / 4;              // 192 blocks per item (4 waves/block)
    int b = blockIdx.x / bpi;
    int wave = threadIdx.x >> 6;
    int lane = threadIdx.x & 63;
    int i = (blockIdx.x % bpi) * 4 + wave;
    const float* bfb = bf + (size_t)b * 5 * RNK;
    float x1 = bfb[0 * RNK + i], x2 = bfb[1 * RNK + i];
    float y1 = bfb[2 * RNK + i], y2 = bfb[3 * RNK + i];
    float ar = bfb[4 * RNK + i];
    u64 myword = 0;
    for (int jw = 0; jw < RW; ++jw) {
        int j = jw * 64 + lane;
        float ix = fminf(x2, bfb[1 * RNK + j]) - fmaxf(x1, bfb[0 * RNK + j]);
        ix = fmaxf(ix, 0.0f);
        float iy = fminf(y2, bfb[3 * RNK + j]) - fmaxf(y1, bfb[2 * RNK + j]);
        iy = fmaxf(iy, 0.0f);
        float inter = __fmul_rn(ix, iy);            // block FMA contraction (match np rounding)
        float uni = (ar + bfb[4 * RNK + j]) - inter;
        float iou = inter / fmaxf(uni, 1e-6f);
        u64 bal = __ballot((iou > TH) && (j > i));
        if (jw == lane) myword = bal;
    }
    if (lane < RW) supt[((size_t)b * RW + lane) * ROWS_A + i] = myword;
}

// 5) fixpoint NMS + output + INLINE exact fallback (4 blocks x 1024).
//    Fast path: Jacobi fixpoint of K[j] = !(exists i: K[i] & sup[i][j]) == greedy
//    (sup[i][j]=0 for j<=i; unique fixpoint by induction). ok = converged &&
//    kept>=POST && rank tile didn't overflow. If !ok: full reference recompute.
__global__ void __launch_bounds__(1024) k_nmsout(const u64* __restrict__ supt,
                                                 const uint32_t* __restrict__ cnt,
                                                 const uint32_t* __restrict__ ccnt,
                                                 const int* __restrict__ sidx,
                                                 const float* __restrict__ ssc,
                                                 const float* __restrict__ box,
                                                 const float* __restrict__ cls,
                                                 u64* __restrict__ fkey,
                                                 u64* __restrict__ fselk,
                                                 u64* __restrict__ fkr,
                                                 float* __restrict__ fbf,
                                                 float* __restrict__ out) {
    int b = blockIdx.x;
    int tid = threadIdx.x;
    __shared__ u64 keepw[RW], nremw[RW];
    __shared__ uint32_t wpre[65];
    __shared__ int s_changed, s_done;
    const u64* sb = supt + (size_t)b * RW * ROWS_A;

    if (tid < RW) keepw[tid] = ~0ull;
    if (tid == 0) s_done = 0;
    __syncthreads();
    for (int it = 0; it < 48; ++it) {
        if (tid < RW) nremw[tid] = 0;
        if (tid == 0) s_changed = 0;
        __syncthreads();
        // 768 tasks: (word w = tau>>6, 12-row chunk (tau&63)*12); coalesced 96B reads
        for (int tau = tid; tau < ROWS_A; tau += 1024) {
            int w = tau >> 6;
            int r0 = (tau & 63) * 12;
            const u64* wp = sb + (size_t)w * ROWS_A;
            u64 acc = 0;
#pragma unroll
            for (int rr = 0; rr < 12; ++rr) {
                int r = r0 + rr;
                if ((keepw[r >> 6] >> (r & 63)) & 1ull) acc |= wp[r];
            }
            if (acc) atomicOr(&nremw[w], acc);
        }
        __syncthreads();
        if (tid < RW) {
            u64 nk = ~nremw[tid];
            if (nk != keepw[tid]) { s_changed = 1; keepw[tid] = nk; }
        }
        __syncthreads();
        if (!s_changed) { if (tid == 0) s_done = 1; break; }   // uniform exit
    }
    __syncthreads();

    if (tid == 0) {
        uint32_t c = 0;
        for (int w = 0; w < RW; ++w) { wpre[w] = c; c += (uint32_t)__popcll(keepw[w]); }
        wpre[RW] = c;
        bool tileok = (cnt[b] + ccnt[b]) <= RS_TILE;
        s_changed = (s_done && c >= POST && tileok) ? 1 : 0;   // "fast path ok"
    }
    __syncthreads();

    if (s_changed) {
        // outputs come only from kept rows at rank<768 (suppressed/late d >= nkeep >= POST)
        for (int r = tid; r < ROWS_A; r += 1024) {
            int w = r >> 6, bit = r & 63;
            u64 word = keepw[w];
            if (!((word >> bit) & 1ull)) continue;
            u64 mask = bit ? ((1ull << bit) - 1ull) : 0ull;
            uint32_t d = wpre[w] + (uint32_t)__popcll(word & mask);
            if (d < POST) {
                float* ro = out + ((size_t)b * POST + d) * 7;
                int n = sidx[b * RNK + r];
                const float* bp = box + ((size_t)b * NN + n) * 7;
#pragma unroll
                for (int t = 0; t < 7; ++t) ro[t] = bp[t];
                out[(size_t)BB * POST * 7 + b * POST + d] = ssc[b * RNK + r];
                const float* cp = cls + ((size_t)b * NN + n) * CC;
                float c0 = cp[0], c1 = cp[1], c2 = cp[2];
                int lbl = 0; float bst = c0;
                if (c1 > bst) { bst = c1; lbl = 1; }
                if (c2 > bst) { lbl = 2; }
                out[(size_t)BB * POST * 8 + b * POST + d] = (float)(lbl + 1);
            }
        }
        return;
    }

    // ---------- exact fallback (reference semantics; proven r12 code) ----------
    size_t bo = (size_t)b * NN;
    for (int n = tid; n < NN; n += 1024)
        fkey[bo + n] = ((u64)f2u(score3(cls + (bo + n) * CC)) << 32)
                     | (uint32_t)(~(uint32_t)n);
    __syncthreads();

    __shared__ uint32_t hist[256];
    __shared__ u64 s_prefix;
    __shared__ uint32_t s_k;
    if (tid == 0) { s_prefix = 0; s_k = PRE; }
    __syncthreads();
    for (int pass = 0; pass < 8; ++pass) {
        if (tid < 256) hist[tid] = 0;
        __syncthreads();
        u64 prefix = s_prefix;
        int hi = 8 * pass;
        for (int i = tid; i < NN; i += 1024) {
            u64 k = fkey[bo + i];
            bool match = (pass == 0) || ((k >> (64 - hi)) == prefix);
            if (match) atomicAdd(&hist[(uint32_t)((k >> (56 - hi)) & 255u)], 1u);
        }
        __syncthreads();
        if (tid == 0) {
            uint32_t kneed = s_k, cum = 0; int chosen = 0;
            for (int d = 255; d >= 0; --d) {
                if (kneed <= cum + hist[d]) { chosen = d; break; }
                cum += hist[d];
            }
            s_k = kneed - cum;
            s_prefix = (prefix << 8) | (u64)(uint32_t)chosen;
        }
        __syncthreads();
    }
    u64 kstar = s_prefix;

    __shared__ uint32_t s_cnt;
    if (tid == 0) s_cnt = 0;
    __syncthreads();
    for (int i = tid; i < NN; i += 1024) {
        u64 k = fkey[bo + i];
        if (k >= kstar) {
            uint32_t pos = atomicAdd(&s_cnt, 1u);
            if (pos < PRE) fselk[(size_t)b * PRE + pos] = k;
        }
    }
    __syncthreads();

    __shared__ u64 tile[1024];
    u64 myk0 = fselk[(size_t)b * PRE + tid];
    u64 myk1 = fselk[(size_t)b * PRE + tid + 1024];
    u64 myk2 = fselk[(size_t)b * PRE + tid + 2048];
    u64 myk3 = fselk[(size_t)b * PRE + tid + 3072];
    int rc0 = 0, rc1 = 0, rc2 = 0, rc3 = 0;
    for (int t0 = 0; t0 < PRE; t0 += 1024) {
        tile[tid] = fselk[(size_t)b * PRE + t0 + tid];
        __syncthreads();
#pragma unroll 8
        for (int j = 0; j < 1024; ++j) {
            u64 t = tile[j];
            rc0 += (t > myk0) ? 1 : 0;
            rc1 += (t > myk1) ? 1 : 0;
            rc2 += (t > myk2) ? 1 : 0;
            rc3 += (t > myk3) ? 1 : 0;
        }
        __syncthreads();
    }
    {
        u64 ks[4] = {myk0, myk1, myk2, myk3};
        int rs[4] = {rc0, rc1, rc2, rc3};
#pragma unroll
        for (int j = 0; j < 4; ++j) {
            u64 k = ks[j]; int r = rs[j];
            fkr[(size_t)b * PRE + r] = k;
            int n = (int)(~(uint32_t)(k & 0xFFFFFFFFull));
            const float* bp = box + ((size_t)b * NN + n) * 7;
            float x = bp[0], y = bp[1], dx = bp[3], dy = bp[4];
            float* fb = fbf + (size_t)b * 5 * PRE;
            fb[0 * PRE + r] = x - dx * 0.5f;
            fb[1 * PRE + r] = x + dx * 0.5f;
            fb[2 * PRE + r] = y - dy * 0.5f;
            fb[3 * PRE + r] = y + dy * 0.5f;
            fb[4 * PRE + r] = dx * dy;
        }
    }
    __syncthreads();

    __shared__ u64 km[64];
    const float* fb = fbf + (size_t)b * 5 * PRE;
    if (tid < 64) km[tid] = ~0ull;
    __syncthreads();
    for (int i = 0; i < PRE - 1; ++i) {
        if ((km[i >> 6] >> (i & 63)) & 1ull) {
            float x1 = fb[0 * PRE + i], x2 = fb[1 * PRE + i];
            float y1 = fb[2 * PRE + i], y2 = fb[3 * PRE + i];
            float ar = fb[4 * PRE + i];
            for (int j = i + 1 + tid; j < PRE; j += 1024) {
                float ix = fminf(x2, fb[1 * PRE + j]) - fmaxf(x1, fb[0 * PRE + j]);
                ix = fmaxf(ix, 0.0f);
                float iy = fminf(y2, fb[3 * PRE + j]) - fmaxf(y1, fb[2 * PRE + j]);
                iy = fmaxf(iy, 0.0f);
                float inter = __fmul_rn(ix, iy);
                float uni = (ar + fb[4 * PRE + j]) - inter;
                float iou = inter / fmaxf(uni, 1e-6f);
                if (iou > TH) atomicAnd(&km[j >> 6], ~(1ull << (j & 63)));
            }
        }
        __syncthreads();
    }

    if (tid == 0) {
        uint32_t c = 0;
        for (int w = 0; w < 64; ++w) { wpre[w] = c; c += (uint32_t)__popcll(km[w]); }
        wpre[64] = c;
    }
    __syncthreads();
    uint32_t nkeep = wpre[64];
    for (int r = tid; r < PRE; r += 1024) {
        int w = r >> 6, bit = r & 63;
        u64 word = km[w];
        bool kept = (word >> bit) & 1ull;
        u64 mask = bit ? ((1ull << bit) - 1ull) : 0ull;
        uint32_t before = wpre[w] + (uint32_t)__popcll(word & mask);
        uint32_t d = kept ? before : (nkeep + (uint32_t)r - before);
        if (d < POST) {
            float* ro = out + ((size_t)b * POST + d) * 7;
            float* so = out + (size_t)BB * POST * 7 + b * POST + d;
            float* lo = out + (size_t)BB * POST * 8 + b * POST + d;
            if (kept) {
                u64 k = fkr[(size_t)b * PRE + r];
                int n = (int)(~(uint32_t)(k & 0xFFFFFFFFull));
                const float* bp = box + ((size_t)b * NN + n) * 7;
#pragma unroll
                for (int t = 0; t < 7; ++t) ro[t] = bp[t];
                *so = u2f((uint32_t)(k >> 32));
                const float* cp = cls + ((size_t)b * NN + n) * CC;
                float c0 = cp[0], c1 = cp[1], c2 = cp[2];
                int lbl = 0; float bst = c0;
                if (c1 > bst) { bst = c1; lbl = 1; }
                if (c2 > bst) { lbl = 2; }
                *lo = (float)(lbl + 1);
            } else {
#pragma unroll
                for (int t = 0; t < 7; ++t) ro[t] = 0.0f;
                *so = 0.0f;
                *lo = 1.0f;
            }
        }
    }
}

extern "C" void kernel_launch(void* const* d_in, const int* in_sizes, int n_in,
                              void* d_out, int out_size, void* d_ws, size_t ws_size,
                              hipStream_t stream) {
    const float* cls = (const float*)d_in[0];   // (4, 32768, 3)
    const float* box = (const float*)d_in[1];   // (4, 32768, 7)
    float* out = (float*)d_out;                 // 18432 floats

    char* ws = (char*)d_ws;
    const size_t KB = 1024, MB = 1024 * 1024;
    // No aliasing: every buffer has its own range.
    size_t OFF_SUPT  = 0;                 // 288 KB
    size_t OFF_HISTF = 512 * KB;          // 1 MB
    size_t OFF_HISTC = 1536 * KB;         // 4 KB (contiguous with hist_f: one k_zero range)
    size_t OFF_CAND  = 1540 * KB;         // 64 KB
    size_t OFF_SELK  = 1604 * KB;         // 24 KB
    size_t OFF_BF    = 1664 * KB;         // 60 KB
    size_t OFF_SIDX  = 1728 * KB;         // 12 KB
    size_t OFF_SSC   = 1740 * KB;         // 12 KB
    size_t OFF_SCAL  = 1752 * KB;         // cnt[4], ccnt[4]
    size_t OFF_FKEY  = 2 * MB;            // 1 MB   (fallback only)
    size_t OFF_FSELK = 3 * MB;            // 128 KB (fallback only)
    size_t OFF_FKR   = 3 * MB + 128 * KB; // 128 KB (fallback only)
    size_t OFF_FBF   = 3 * MB + 256 * KB; // 320 KB (fallback only)

    u64*      supt   = (u64*)(ws + OFF_SUPT);
    uint32_t* hist_f = (uint32_t*)(ws + OFF_HISTF);
    uint32_t* hist_c = (uint32_t*)(ws + OFF_HISTC);
    u64*      cand   = (u64*)(ws + OFF_CAND);
    u64*      selk   = (u64*)(ws + OFF_SELK);
    float*    bf     = (float*)(ws + OFF_BF);
    int*      sidx   = (int*)(ws + OFF_SIDX);
    float*    ssc    = (float*)(ws + OFF_SSC);
    uint32_t* scal   = (uint32_t*)(ws + OFF_SCAL);
    uint32_t* cnt    = scal;
    uint32_t* ccnt   = scal + 4;
    u64*      fkey   = (u64*)(ws + OFF_FKEY);
    u64*      fselk  = (u64*)(ws + OFF_FSELK);
    u64*      fkr    = (u64*)(ws + OFF_FKR);
    float*    fbf    = (float*)(ws + OFF_FBF);

    // 6-dispatch chain (the empirically fastest configuration: r15):
    int n16 = (int)((MB + 4 * KB) / 16);   // hist_f + hist_c, 65792 uint4
    k_zero<<<(n16 + 255) / 256, 256, 0, stream>>>((uint4*)(ws + OFF_HISTF), scal, n16);
    k_hist<<<(BB * NN) / 256, 256, 0, stream>>>(cls, hist_f, hist_c);
    k_collect<<<(BB * NN) / 256, 256, 0, stream>>>(cls, hist_c, hist_f, cnt, ccnt, selk, cand);
    k_rankscatter<<<BB * (RS_TILE / 64), 256, 0, stream>>>(selk, cand, cnt, ccnt,
                                                           box, sidx, ssc, bf);
    k_iou<<<(ROWS_A / 4) * BB, 256, 0, stream>>>(bf, supt);
    k_nmsout<<<BB, 1024, 0, stream>>>(supt, cnt, ccnt, sidx, ssc, box, cls,
                                      fkey, fselk, fkr, fbf, out);
}